// Round 4
// baseline (138.542 us; speedup 1.0000x reference)
//
#include <hip/hip_runtime.h>

#define NORG 13
#define NCH  14
#define VOX  (48 * 256 * 256)   // voxels per (batch, channel) plane
#define EPSF 1e-5f
#define CHUNK 4096              // voxels per block
#define NCHUNK (VOX / CHUNK)    // 768 chunks per batch -> 1536 blocks
#define ITER (CHUNK / 4 / 256)  // 4 float4-iterations per pass
#define COMBO_STRIDE 16         // padded ws slots per (replica, b, organ)
#define NREP 4                  // global accumulator replicas (atomic spread)

__global__ __launch_bounds__(256) void dice_partial(
    const float* __restrict__ pred1, const float* __restrict__ pred2,
    const int* __restrict__ tgt, float* __restrict__ acc_out)
{
    const int b     = blockIdx.y;
    const int chunk = blockIdx.x;
    const size_t v0 = (size_t)chunk * CHUNK;

    __shared__ unsigned char t_lds[CHUNK];    // target chunk, staged ONCE
    __shared__ float red[4][16][NORG * 5];    // per (wave, 4-lane-group) partials

    // ---- stage target chunk into LDS as uchar ----
    const int4* tb = (const int4*)(tgt + (size_t)b * VOX + v0);
    uchar4* tl4 = (uchar4*)t_lds;
#pragma unroll
    for (int i = 0; i < ITER; ++i) {
        const int4 t = tb[i * 256 + threadIdx.x];
        tl4[i * 256 + threadIdx.x] =
            make_uchar4((unsigned char)t.x, (unsigned char)t.y,
                        (unsigned char)t.z, (unsigned char)t.w);
    }
    __syncthreads();

    const uchar4* tl = (const uchar4*)t_lds;
    const int lane = threadIdx.x & 63;
    const int wid  = threadIdx.x >> 6;

    // ---- 13 channel passes, both stages fused (2 HBM streams per pass) ----
    for (int o = 0; o < NORG; ++o) {
        const int ch = o + 1;
        const float4* p1 = (const float4*)(pred1 + ((size_t)b * NCH + ch) * VOX + v0);
        const float4* p2 = (const float4*)(pred2 + ((size_t)b * NCH + ch) * VOX + v0);

        float i1 = 0.f, s1 = 0.f, i2 = 0.f, s2 = 0.f, cn = 0.f;
#pragma unroll
        for (int i = 0; i < ITER; ++i) {
            const int idx = i * 256 + threadIdx.x;
            const uchar4 t = tl[idx];
            const float4 a = p1[idx];
            const float4 c = p2[idx];
            const float m0 = (t.x == ch) ? 1.f : 0.f;
            const float m1 = (t.y == ch) ? 1.f : 0.f;
            const float m2 = (t.z == ch) ? 1.f : 0.f;
            const float m3 = (t.w == ch) ? 1.f : 0.f;
            s1 += a.x * a.x + a.y * a.y + a.z * a.z + a.w * a.w;
            s2 += c.x * c.x + c.y * c.y + c.z * c.z + c.w * c.w;
            i1 += m0 * a.x + m1 * a.y + m2 * a.z + m3 * a.w;
            i2 += m0 * c.x + m1 * c.y + m2 * c.z + m3 * c.w;
            cn += (m0 + m1) + (m2 + m3);
        }

        // cheap tail: 2-level shuffle (sum within 4-lane groups), then a
        // plain ds_write of 16 partials/wave -- no atomics, no deep chain
        float vals[5] = {i1, s1, i2, s2, cn};
#pragma unroll
        for (int s = 0; s < 5; ++s) {
            float r = vals[s];
            r += __shfl_xor(r, 1, 64);
            r += __shfl_xor(r, 2, 64);
            if ((lane & 3) == 0) red[wid][lane >> 2][o * 5 + s] = r;
        }
    }

    __syncthreads();
    // block-end combine: 65 slots, each summed over 64 (wave,group) partials,
    // then one global atomic per slot into one of NREP replica banks
    if (threadIdx.x < NORG * 5) {
        float s = 0.f;
#pragma unroll
        for (int w = 0; w < 4; ++w)
#pragma unroll
            for (int g = 0; g < 16; ++g)
                s += red[w][g][threadIdx.x];
        const int o  = threadIdx.x / 5;
        const int sl = threadIdx.x % 5;
        const int bo = b * NORG + o;
        const int rep = blockIdx.x & (NREP - 1);
        atomicAdd(&acc_out[(rep * 26 + bo) * COMBO_STRIDE + sl], s);
    }
}

__global__ void dice_final(const float* __restrict__ acc,
                           float* __restrict__ out, int B)
{
    if (threadIdx.x == 0 && blockIdx.x == 0) {
        float total = 0.f;
        for (int b = 0; b < B; ++b) {
            float d1 = 0.f, d2 = 0.f;
            for (int o = 0; o < NORG; ++o) {
                const int bo = b * NORG + o;
                float a0 = 0.f, a1 = 0.f, a2 = 0.f, a3 = 0.f, a4 = 0.f;
                for (int r = 0; r < NREP; ++r) {
                    const float* a = acc + (r * 26 + bo) * COMBO_STRIDE;
                    a0 += a[0]; a1 += a[1]; a2 += a[2]; a3 += a[3]; a4 += a[4];
                }
                d1 += 2.f * a0 / (a1 + a4 + EPSF);
                d2 += 2.f * a2 / (a3 + a4 + EPSF);
            }
            total += 2.f - (d1 + d2) / (float)NORG;
        }
        out[0] = total / (float)B;
    }
}

extern "C" void kernel_launch(void* const* d_in, const int* in_sizes, int n_in,
                              void* d_out, int out_size, void* d_ws, size_t ws_size,
                              hipStream_t stream)
{
    const float* p1  = (const float*)d_in[0];
    const float* p2  = (const float*)d_in[1];
    const int*   tgt = (const int*)d_in[2];
    float*       out = (float*)d_out;
    float*       acc = (float*)d_ws;

    const int B = in_sizes[2] / VOX;   // = 2 for the reference shapes

    // zero all replica accumulator banks (ws poisoned once, never re-zeroed)
    hipMemsetAsync(d_ws, 0,
                   (size_t)NREP * 26 * COMBO_STRIDE * sizeof(float), stream);

    dim3 grid(NCHUNK, B);              // 768 x 2 = 1536 blocks, ~6/CU
    dice_partial<<<grid, 256, 0, stream>>>(p1, p2, tgt, acc);
    dice_final<<<1, 64, 0, stream>>>(acc, out, B);
}

// Round 5
// 125.004 us; speedup vs baseline: 1.1083x; 1.1083x over previous
//
#include <hip/hip_runtime.h>

#define NORG 13
#define NCH  14
#define VOX  (48 * 256 * 256)   // voxels per (batch, channel) plane
#define EPSF 1e-5f
#define CHUNK 8192              // voxels per block (best measured: round 2)
#define NCHUNK (VOX / CHUNK)    // 384 chunks per batch -> 768 blocks
#define ITER (CHUNK / 4 / 256)  // 8 float4-iterations per pass
#define COMBO_STRIDE 16         // padded ws slots per (replica, b, organ)
#define NREP 4                  // global accumulator replicas

typedef float f4 __attribute__((ext_vector_type(4)));
typedef int   i4 __attribute__((ext_vector_type(4)));

__global__ __launch_bounds__(256) void dice_partial(
    const float* __restrict__ pred1, const float* __restrict__ pred2,
    const int* __restrict__ tgt, float* __restrict__ acc_out)
{
    const int b     = blockIdx.y;
    const int chunk = blockIdx.x;
    const size_t v0 = (size_t)chunk * CHUNK;

    __shared__ unsigned char t_lds[CHUNK];    // target chunk, staged ONCE
    __shared__ float red[4][16][NORG * 5];    // per (wave, 4-lane-group) partials

    // ---- stage target chunk into LDS as uchar (nontemporal: read-once) ----
    const i4* tb = (const i4*)(tgt + (size_t)b * VOX + v0);
    uchar4* tl4 = (uchar4*)t_lds;
#pragma unroll
    for (int i = 0; i < ITER; ++i) {
        const i4 t = __builtin_nontemporal_load(tb + i * 256 + threadIdx.x);
        tl4[i * 256 + threadIdx.x] =
            make_uchar4((unsigned char)t.x, (unsigned char)t.y,
                        (unsigned char)t.z, (unsigned char)t.w);
    }
    __syncthreads();

    const uchar4* tl = (const uchar4*)t_lds;
    const int lane = threadIdx.x & 63;
    const int wid  = threadIdx.x >> 6;

    // ---- 13 channel passes, both stages fused (2 HBM streams per pass) ----
    for (int o = 0; o < NORG; ++o) {
        const int ch = o + 1;
        const f4* p1 = (const f4*)(pred1 + ((size_t)b * NCH + ch) * VOX + v0);
        const f4* p2 = (const f4*)(pred2 + ((size_t)b * NCH + ch) * VOX + v0);

        float i1 = 0.f, s1 = 0.f, i2 = 0.f, s2 = 0.f, cn = 0.f;
#pragma unroll
        for (int i = 0; i < ITER; ++i) {
            const int idx = i * 256 + threadIdx.x;
            const uchar4 t = tl[idx];
            const f4 a = __builtin_nontemporal_load(p1 + idx);
            const f4 c = __builtin_nontemporal_load(p2 + idx);
            const float m0 = (t.x == ch) ? 1.f : 0.f;
            const float m1 = (t.y == ch) ? 1.f : 0.f;
            const float m2 = (t.z == ch) ? 1.f : 0.f;
            const float m3 = (t.w == ch) ? 1.f : 0.f;
            s1 += a.x * a.x + a.y * a.y + a.z * a.z + a.w * a.w;
            s2 += c.x * c.x + c.y * c.y + c.z * c.z + c.w * c.w;
            i1 += m0 * a.x + m1 * a.y + m2 * a.z + m3 * a.w;
            i2 += m0 * c.x + m1 * c.y + m2 * c.z + m3 * c.w;
            cn += (m0 + m1) + (m2 + m3);
        }

        // cheap tail: 2-level shuffle (4-lane groups) + plain ds_write
        float vals[5] = {i1, s1, i2, s2, cn};
#pragma unroll
        for (int s = 0; s < 5; ++s) {
            float r = vals[s];
            r += __shfl_xor(r, 1, 64);
            r += __shfl_xor(r, 2, 64);
            if ((lane & 3) == 0) red[wid][lane >> 2][o * 5 + s] = r;
        }
    }

    __syncthreads();
    // block-end combine: 65 slots x 64 partials, one global atomic per slot
    if (threadIdx.x < NORG * 5) {
        float s = 0.f;
#pragma unroll
        for (int w = 0; w < 4; ++w)
#pragma unroll
            for (int g = 0; g < 16; ++g)
                s += red[w][g][threadIdx.x];
        const int o  = threadIdx.x / 5;
        const int sl = threadIdx.x % 5;
        const int bo = b * NORG + o;
        const int rep = blockIdx.x & (NREP - 1);
        atomicAdd(&acc_out[(rep * 26 + bo) * COMBO_STRIDE + sl], s);
    }
}

__global__ void dice_final(const float* __restrict__ acc,
                           float* __restrict__ out, int B)
{
    if (threadIdx.x == 0 && blockIdx.x == 0) {
        float total = 0.f;
        for (int b = 0; b < B; ++b) {
            float d1 = 0.f, d2 = 0.f;
            for (int o = 0; o < NORG; ++o) {
                const int bo = b * NORG + o;
                float a0 = 0.f, a1 = 0.f, a2 = 0.f, a3 = 0.f, a4 = 0.f;
                for (int r = 0; r < NREP; ++r) {
                    const float* a = acc + (r * 26 + bo) * COMBO_STRIDE;
                    a0 += a[0]; a1 += a[1]; a2 += a[2]; a3 += a[3]; a4 += a[4];
                }
                d1 += 2.f * a0 / (a1 + a4 + EPSF);
                d2 += 2.f * a2 / (a3 + a4 + EPSF);
            }
            total += 2.f - (d1 + d2) / (float)NORG;
        }
        out[0] = total / (float)B;
    }
}

extern "C" void kernel_launch(void* const* d_in, const int* in_sizes, int n_in,
                              void* d_out, int out_size, void* d_ws, size_t ws_size,
                              hipStream_t stream)
{
    const float* p1  = (const float*)d_in[0];
    const float* p2  = (const float*)d_in[1];
    const int*   tgt = (const int*)d_in[2];
    float*       out = (float*)d_out;
    float*       acc = (float*)d_ws;

    const int B = in_sizes[2] / VOX;   // = 2 for the reference shapes

    // zero all replica accumulator banks (ws poisoned once, never re-zeroed)
    hipMemsetAsync(d_ws, 0,
                   (size_t)NREP * 26 * COMBO_STRIDE * sizeof(float), stream);

    dim3 grid(NCHUNK, B);              // 384 x 2 = 768 blocks
    dice_partial<<<grid, 256, 0, stream>>>(p1, p2, tgt, acc);
    dice_final<<<1, 64, 0, stream>>>(acc, out, B);
}